// Round 10
// baseline (680.763 us; speedup 1.0000x reference)
//
#include <hip/hip_runtime.h>
#include <algorithm>

#define FIN 24
#define NHID 64
#define NMIX 216
#define NOUT 6
#define BN_EPS 1e-5f

// ---------- CSR build ----------
__global__ void k_hist(const int* __restrict__ ei, int E, int* deg) {
    int e = blockIdx.x * blockDim.x + threadIdx.x;
    if (e < E) atomicAdd(&deg[ei[E + e]], 1);
}

// block-local exclusive scan over deg (n+1 elements, deg[i>=n]:=0); totals -> bsum
// also emits dis[i] = 1/sqrt(deg[i]) (0 if empty)
__global__ void k_scan_local(const int* __restrict__ deg, int n, int* rowptr, int* bsum,
                             float* __restrict__ dis) {
    __shared__ int s[256];
    int i = blockIdx.x * 256 + threadIdx.x;
    int v = (i < n) ? deg[i] : 0;
    if (i < n) dis[i] = v > 0 ? rsqrtf((float)v) : 0.f;
    s[threadIdx.x] = v;
    __syncthreads();
#pragma unroll
    for (int off = 1; off < 256; off <<= 1) {
        int x = (threadIdx.x >= off) ? s[threadIdx.x - off] : 0;
        __syncthreads();
        s[threadIdx.x] += x;
        __syncthreads();
    }
    if (i <= n) rowptr[i] = s[threadIdx.x] - v;  // exclusive
    if (threadIdx.x == 255) bsum[blockIdx.x] = s[255];
}

__global__ void k_scan_bsum(int* bsum, int nb) {
    __shared__ int s[256];
    int carry = 0;
    for (int base = 0; base < nb; base += 256) {
        int i = base + threadIdx.x;
        int v = (i < nb) ? bsum[i] : 0;
        s[threadIdx.x] = v;
        __syncthreads();
#pragma unroll
        for (int off = 1; off < 256; off <<= 1) {
            int x = (threadIdx.x >= off) ? s[threadIdx.x - off] : 0;
            __syncthreads();
            s[threadIdx.x] += x;
            __syncthreads();
        }
        if (i < nb) bsum[i] = s[threadIdx.x] - v + carry;
        carry += s[255];
        __syncthreads();
    }
}

__global__ void k_scan_add(int* rowptr, const int* __restrict__ bsum, int n) {
    int i = blockIdx.x * 256 + threadIdx.x;
    if (i <= n) rowptr[i] += bsum[blockIdx.x];
}

// fill CSR with packed (col, val) per edge
__global__ void k_fill(const int* __restrict__ ei, int E, const float* __restrict__ dis,
                       const int* __restrict__ rowptr, int* fill, int2* __restrict__ cv) {
    int e = blockIdx.x * blockDim.x + threadIdx.x;
    if (e >= E) return;
    int s = ei[e], d = ei[E + e];
    int slot = rowptr[d] + atomicAdd(&fill[d], 1);
    cv[slot] = make_int2(s, __float_as_int(-dis[s] * dis[d]));
}

// transpose 3 Cheb weight sets: W [6][24][64] -> Wt [6][64][24]
__global__ void k_wt3(const float* __restrict__ Wa, float* __restrict__ Ta,
                      const float* __restrict__ Wb, float* __restrict__ Tb,
                      const float* __restrict__ Wc, float* __restrict__ Tc) {
    int o = blockIdx.x * blockDim.x + threadIdx.x;  // 0 .. 3*9216-1
    int which = o / 9216, oo = o - which * 9216;
    const float* W = (which == 0) ? Wa : (which == 1) ? Wb : Wc;
    float* T       = (which == 0) ? Ta : (which == 1) ? Tb : Tc;
    int k = oo / 1536, r = oo - k * 1536;
    int j = r / FIN, f = r - j * FIN;
    T[oo] = W[k * 1536 + f * NHID + j];
}

// ---------- gather prop, thread per (dst node, float4 chunk) ----------
__global__ void k_propg(const int* __restrict__ rowptr, const int2* __restrict__ cv,
                        float scale, const float* __restrict__ h,
                        const float* __restrict__ prev, float* __restrict__ out, int n) {
    int idx = blockIdx.x * blockDim.x + threadIdx.x;
    if (idx >= n * 6) return;
    int d = idx / 6, q = idx - d * 6;
    int beg = rowptr[d], end = rowptr[d + 1];
    const float4* h4 = reinterpret_cast<const float4*>(h);
    float ax = 0.f, ay = 0.f, az = 0.f, aw = 0.f;
    float bx = 0.f, by = 0.f, bz = 0.f, bw = 0.f;
    int e = beg;
    for (; e + 2 <= end; e += 2) {
        int2 c0 = cv[e], c1 = cv[e + 1];
        float w0 = __int_as_float(c0.y), w1 = __int_as_float(c1.y);
        float4 h0 = h4[(size_t)c0.x * 6 + q];
        float4 h1 = h4[(size_t)c1.x * 6 + q];
        ax = fmaf(w0, h0.x, ax); ay = fmaf(w0, h0.y, ay);
        az = fmaf(w0, h0.z, az); aw = fmaf(w0, h0.w, aw);
        bx = fmaf(w1, h1.x, bx); by = fmaf(w1, h1.y, by);
        bz = fmaf(w1, h1.z, bz); bw = fmaf(w1, h1.w, bw);
    }
    if (e < end) {
        int2 c0 = cv[e];
        float w0 = __int_as_float(c0.y);
        float4 h0 = h4[(size_t)c0.x * 6 + q];
        ax = fmaf(w0, h0.x, ax); ay = fmaf(w0, h0.y, ay);
        az = fmaf(w0, h0.z, az); aw = fmaf(w0, h0.w, aw);
    }
    ax += bx; ay += by; az += bz; aw += bw;
    float4 r;
    if (prev) {
        float4 pv = reinterpret_cast<const float4*>(prev)[idx];
        r = make_float4(fmaf(scale, ax, -pv.x), fmaf(scale, ay, -pv.y),
                        fmaf(scale, az, -pv.z), fmaf(scale, aw, -pv.w));
    } else {
        r = make_float4(scale * ax, scale * ay, scale * az, scale * aw);
    }
    reinterpret_cast<float4*>(out)[idx] = r;
}

// acc[node][j] (=|+=) S1@Wa + S2@Wb (+bias); lane=j, wave-uniform node.
// Wave-local LDS staging of S rows; W given TRANSPOSED ([64][24]) so lane j's
// 24 weights are 6 contiguous float4 loads (register-resident or cheap reload).
__global__ void k_gemv2(const float* __restrict__ S1, const float* __restrict__ S2,
                        const float* __restrict__ Wta, const float* __restrict__ Wtb,
                        const float* __restrict__ bias, float* __restrict__ acc,
                        float* __restrict__ stats, int n) {
    __shared__ float sb[4][2][16 * FIN];  // [wave][S1/S2][16 nodes * 24 floats] = 12 KB
    int j = threadIdx.x & 63;
    int w = threadIdx.x >> 6;
    int nbase = blockIdx.x * 64 + w * 16;
    // ---- W columns for lane j: contiguous 96B each, 6 float4 per matrix ----
    float4 wa4[6], wb4[6];
    {
        const float4* pa = reinterpret_cast<const float4*>(Wta + j * FIN);
        const float4* pb = reinterpret_cast<const float4*>(Wtb + j * FIN);
#pragma unroll
        for (int t = 0; t < 6; ++t) { wa4[t] = pa[t]; wb4[t] = pb[t]; }
    }
    // ---- stage: 192 float4 per wave (96 per S-half = 16 nodes * 6); 3 per lane ----
#pragma unroll
    for (int k = 0; k < 3; ++k) {
        int i = k * 64 + j;            // 0..191
        int half = i / 96;             // 0: S1, 1: S2
        int j4 = i - half * 96;        // 0..95
        int nd = j4 / 6, q = j4 - nd * 6;   // nd: 0..15, q: 0..5
        int node = nbase + nd;
        const float* src = (half ? S2 : S1) + (size_t)node * FIN + q * 4;
        float4 v = (node < n) ? *reinterpret_cast<const float4*>(src)
                              : make_float4(0.f, 0.f, 0.f, 0.f);
        *reinterpret_cast<float4*>(&sb[w][half][j4 * 4]) = v;
    }
    // ---- compute 16 nodes ----
    float sum = 0.f, sq = 0.f;
#pragma unroll 2
    for (int nd = 0; nd < 16; ++nd) {
        int node = nbase + nd;
        bool ok = (node < n);
        float base = bias ? bias[j] : (ok ? acc[(size_t)node * NHID + j] : 0.f);
        const float4* r1 = reinterpret_cast<const float4*>(&sb[w][0][nd * FIN]);
        const float4* r2 = reinterpret_cast<const float4*>(&sb[w][1][nd * FIN]);
        float a = 0.f, p = 0.f;
#pragma unroll
        for (int t = 0; t < 6; ++t) {
            float4 v = r1[t];
            a = fmaf(v.x, wa4[t].x, a);
            p = fmaf(v.y, wa4[t].y, p);
            a = fmaf(v.z, wa4[t].z, a);
            p = fmaf(v.w, wa4[t].w, p);
        }
#pragma unroll
        for (int t = 0; t < 6; ++t) {
            float4 v = r2[t];
            a = fmaf(v.x, wb4[t].x, a);
            p = fmaf(v.y, wb4[t].y, p);
            a = fmaf(v.z, wb4[t].z, a);
            p = fmaf(v.w, wb4[t].w, p);
        }
        float r = base + a + p;
        if (ok) {
            acc[(size_t)node * NHID + j] = r;
            sum += r; sq = fmaf(r, r, sq);
        }
    }
    if (stats) {
        __shared__ float rs[256], rq[256];
        rs[threadIdx.x] = sum; rq[threadIdx.x] = sq;
        __syncthreads();
        if (threadIdx.x < 64) {
            float s = rs[threadIdx.x] + rs[threadIdx.x + 64] + rs[threadIdx.x + 128] + rs[threadIdx.x + 192];
            float q = rq[threadIdx.x] + rq[threadIdx.x + 64] + rq[threadIdx.x + 128] + rq[threadIdx.x + 192];
            atomicAdd(&stats[threadIdx.x], s);
            atomicAdd(&stats[NHID + threadIdx.x], q);
        }
    }
}

// BN coefficients for all 3 branches: scX[0:64]=scale, scX[64:128]=shift
__global__ void k_bnprep3(const float* __restrict__ st1, const float* __restrict__ g1,
                          const float* __restrict__ bt1, float inv1,
                          const float* __restrict__ st2, const float* __restrict__ g2,
                          const float* __restrict__ bt2, float inv2,
                          const float* __restrict__ st3, const float* __restrict__ g3,
                          const float* __restrict__ bt3, float inv3,
                          float* __restrict__ s1, float* __restrict__ s2,
                          float* __restrict__ s3) {
    int b = threadIdx.x >> 6, i = threadIdx.x & 63;
    const float* st = (b == 0) ? st1 : (b == 1) ? st2 : st3;
    const float* g  = (b == 0) ? g1  : (b == 1) ? g2  : g3;
    const float* bt = (b == 0) ? bt1 : (b == 1) ? bt2 : bt3;
    float inv       = (b == 0) ? inv1 : (b == 1) ? inv2 : inv3;
    float* so       = (b == 0) ? s1  : (b == 1) ? s2  : s3;
    float m = st[i] * inv;
    float v = st[NHID + i] * inv - m * m;
    float sc = g[i] * rsqrtf(v + BN_EPS);
    so[i] = sc;
    so[NHID + i] = fmaf(-m, sc, bt[i]);
}

// segment-mean scatter
__global__ void k_scatter(const float* __restrict__ x, const int* __restrict__ cl,
                          int n, float* xp, float* cnt) {
    int idx = blockIdx.x * blockDim.x + threadIdx.x;
    if (idx >= n * FIN) return;
    int node = idx / FIN, f = idx - node * FIN;
    int c = cl[node];
    atomicAdd(&xp[c * FIN + f], x[idx]);
    if (f == 0) atomicAdd(&cnt[c], 1.f);
}

__global__ void k_divcnt(float* xp, const float* __restrict__ cnt, int c) {
    int idx = blockIdx.x * blockDim.x + threadIdx.x;
    if (idx >= c * FIN) return;
    xp[idx] = xp[idx] / fmaxf(cnt[idx / FIN], 1.f);
}

// fused mix: thread per node; BN+ReLU for all three branches via precomputed
// scale/shift (uniform scalar loads); Wm/bm scalar-indexed.
__global__ void k_final(const float* __restrict__ acc1, const float* __restrict__ sc1,
                        const float* __restrict__ h2, const float* __restrict__ sc2,
                        const int* __restrict__ cl1,
                        const float* __restrict__ h3, const float* __restrict__ sc3,
                        const int* __restrict__ cl2,
                        const float* __restrict__ x, const float* __restrict__ Wm,
                        const float* __restrict__ bm, float* __restrict__ out, int n) {
    int t = blockIdx.x * blockDim.x + threadIdx.x;
    if (t >= n) return;
    float o[NOUT];
#pragma unroll
    for (int j = 0; j < NOUT; ++j) o[j] = bm[j];
    {
        const float4* r4 = reinterpret_cast<const float4*>(acc1 + (size_t)t * NHID);
#pragma unroll
        for (int i4 = 0; i4 < NHID / 4; ++i4) {
            float4 v = r4[i4];
            float hv[4] = {v.x, v.y, v.z, v.w};
#pragma unroll
            for (int c = 0; c < 4; ++c) {
                int i = i4 * 4 + c;
                float h = fmaxf(fmaf(hv[c], sc1[i], sc1[NHID + i]), 0.f);
#pragma unroll
                for (int j = 0; j < NOUT; ++j) o[j] = fmaf(h, Wm[i * NOUT + j], o[j]);
            }
        }
    }
    {
        const float4* r4 = reinterpret_cast<const float4*>(h2 + (size_t)cl1[t] * NHID);
#pragma unroll
        for (int i4 = 0; i4 < NHID / 4; ++i4) {
            float4 v = r4[i4];
            float hv[4] = {v.x, v.y, v.z, v.w};
#pragma unroll
            for (int c = 0; c < 4; ++c) {
                int hid = i4 * 4 + c;
                float h = fmaxf(fmaf(hv[c], sc2[hid], sc2[NHID + hid]), 0.f);
#pragma unroll
                for (int j = 0; j < NOUT; ++j) o[j] = fmaf(h, Wm[(NHID + hid) * NOUT + j], o[j]);
            }
        }
    }
    {
        const float4* r4 = reinterpret_cast<const float4*>(h3 + (size_t)cl2[t] * NHID);
#pragma unroll
        for (int i4 = 0; i4 < NHID / 4; ++i4) {
            float4 v = r4[i4];
            float hv[4] = {v.x, v.y, v.z, v.w};
#pragma unroll
            for (int c = 0; c < 4; ++c) {
                int hid = i4 * 4 + c;
                float h = fmaxf(fmaf(hv[c], sc3[hid], sc3[NHID + hid]), 0.f);
#pragma unroll
                for (int j = 0; j < NOUT; ++j) o[j] = fmaf(h, Wm[(2 * NHID + hid) * NOUT + j], o[j]);
            }
        }
    }
    {
        const float4* r4 = reinterpret_cast<const float4*>(x + (size_t)t * FIN);
#pragma unroll
        for (int i4 = 0; i4 < FIN / 4; ++i4) {
            float4 v = r4[i4];
            float hv[4] = {v.x, v.y, v.z, v.w};
#pragma unroll
            for (int c = 0; c < 4; ++c) {
                int i = 3 * NHID + i4 * 4 + c;
#pragma unroll
                for (int j = 0; j < NOUT; ++j) o[j] = fmaf(hv[c], Wm[i * NOUT + j], o[j]);
            }
        }
    }
    float* op = out + (size_t)t * NOUT;
#pragma unroll
    for (int j = 0; j < NOUT; ++j) op[j] = o[j];
}

extern "C" void kernel_launch(void* const* d_in, const int* in_sizes, int n_in,
                              void* d_out, int out_size, void* d_ws, size_t ws_size,
                              hipStream_t stream) {
    const int N = 200000, E = 800000;
    const int C1n = 20000, E1 = 80000;
    const int C2n = 2000, E2 = 8000;

    const float* x  = (const float*)d_in[0];
    const int* ei   = (const int*)d_in[1];
    const int* cl1  = (const int*)d_in[2];
    const int* cl2  = (const int*)d_in[3];
    const int* eic1 = (const int*)d_in[4];
    const int* eic2 = (const int*)d_in[5];
    const float* W1 = (const float*)d_in[6];  const float* b1 = (const float*)d_in[7];
    const float* g1 = (const float*)d_in[8];  const float* bt1 = (const float*)d_in[9];
    const float* W2 = (const float*)d_in[10]; const float* b2 = (const float*)d_in[11];
    const float* g2 = (const float*)d_in[12]; const float* bt2 = (const float*)d_in[13];
    const float* W3 = (const float*)d_in[14]; const float* b3 = (const float*)d_in[15];
    const float* g3 = (const float*)d_in[16]; const float* bt3 = (const float*)d_in[17];
    const float* Wm = (const float*)d_in[18]; const float* bm = (const float*)d_in[19];

    char* wb = (char*)d_ws;
    size_t off = 0;
    auto alloc = [&](size_t nwords) {
        void* p = wb + off; off += ((nwords + 3) & ~(size_t)3) * 4; return p;
    };
    // --- zero-region ---
    int* degi1 = (int*)alloc(N);   int* fill1 = (int*)alloc(N);
    int* degi2 = (int*)alloc(C1n); int* fill2 = (int*)alloc(C1n);
    int* degi3 = (int*)alloc(C2n); int* fill3 = (int*)alloc(C2n);
    float* st1 = (float*)alloc(128); float* st2 = (float*)alloc(128); float* st3 = (float*)alloc(128);
    float* xp1 = (float*)alloc((size_t)C1n * FIN); float* cnt1 = (float*)alloc(C1n);
    float* xp2 = (float*)alloc((size_t)C2n * FIN); float* cnt2 = (float*)alloc(C2n);
    size_t zero_bytes = off;
    // --- fully-overwritten region ---
    int* rp1 = (int*)alloc(N + 1);   int2* cv1 = (int2*)alloc(2 * (size_t)E);
    int* rp2 = (int*)alloc(C1n + 1); int2* cv2 = (int2*)alloc(2 * (size_t)E1);
    int* rp3 = (int*)alloc(C2n + 1); int2* cv3 = (int2*)alloc(2 * (size_t)E2);
    float* dis1 = (float*)alloc(N); float* dis2 = (float*)alloc(C1n); float* dis3 = (float*)alloc(C2n);
    int* bsum = (int*)alloc(1024);
    float* scsh1 = (float*)alloc(128); float* scsh2 = (float*)alloc(128); float* scsh3 = (float*)alloc(128);
    float* Wt1 = (float*)alloc(9216); float* Wt2 = (float*)alloc(9216); float* Wt3 = (float*)alloc(9216);
    float* B1_0 = (float*)alloc((size_t)N * FIN);   float* B1_1 = (float*)alloc((size_t)N * FIN);
    float* B2_0 = (float*)alloc((size_t)C1n * FIN); float* B2_1 = (float*)alloc((size_t)C1n * FIN);
    float* B3_0 = (float*)alloc((size_t)C2n * FIN); float* B3_1 = (float*)alloc((size_t)C2n * FIN);
    float* acc1 = (float*)alloc((size_t)N * NHID);
    float* acc2 = (float*)alloc((size_t)C1n * NHID);
    float* acc3 = (float*)alloc((size_t)C2n * NHID);
    if (off > ws_size) return;  // fail visibly if ws too small

    hipMemsetAsync(d_ws, 0, zero_bytes, stream);

    const int T = 256;
    auto cdiv = [](int a, int b) { return (a + b - 1) / b; };

    // transpose all Cheb weights up front (independent of everything else)
    k_wt3<<<cdiv(3 * 9216, T), T, 0, stream>>>(W1, Wt1, W2, Wt2, W3, Wt3);

    auto branch = [&](const float* xin, int n, const int* e, int Ecnt,
                      const float* Wt, const float* bb, int* degi, int* fill, float* dis,
                      int* rp, int2* cv, float* B0, float* Bb1, float* acc, float* st) {
        int ge = cdiv(Ecnt, T), gn = cdiv(n, T);
        int nb = cdiv(n + 1, 256);
        int gg = cdiv(n, 64);        // gemv: one 64-node tile per block
        int gp = cdiv(n * 6, T);     // propg: thread per (node, chunk)
        const int WSZ = NHID * FIN;  // per-k transposed block
        // CSR build
        k_hist<<<ge, T, 0, stream>>>(e, Ecnt, degi);
        k_scan_local<<<nb, 256, 0, stream>>>(degi, n, rp, bsum, dis);
        k_scan_bsum<<<1, 256, 0, stream>>>(bsum, nb);
        k_scan_add<<<nb, 256, 0, stream>>>(rp, bsum, n);
        k_fill<<<ge, T, 0, stream>>>(e, Ecnt, dis, rp, fill, cv);
        // Tx1 = P(x) -> B0
        k_propg<<<gp, T, 0, stream>>>(rp, cv, 1.0f, xin, nullptr, B0, n);
        // acc = b + x@W0 + Tx1@W1
        k_gemv2<<<gg, T, 0, stream>>>(xin, B0, Wt, Wt + WSZ, bb, acc, nullptr, n);
        // Tx2 = 2P(Tx1) - x -> Bb1
        k_propg<<<gp, T, 0, stream>>>(rp, cv, 2.0f, B0, xin, Bb1, n);
        // Tx3 = 2P(Tx2) - Tx1 -> B0 (in place over prev)
        k_propg<<<gp, T, 0, stream>>>(rp, cv, 2.0f, Bb1, B0, B0, n);
        // acc += Tx2@W2 + Tx3@W3
        k_gemv2<<<gg, T, 0, stream>>>(Bb1, B0, Wt + 2 * WSZ, Wt + 3 * WSZ, nullptr, acc, nullptr, n);
        // Tx4 = 2P(Tx3) - Tx2 -> Bb1
        k_propg<<<gp, T, 0, stream>>>(rp, cv, 2.0f, B0, Bb1, Bb1, n);
        // Tx5 = 2P(Tx4) - Tx3 -> B0
        k_propg<<<gp, T, 0, stream>>>(rp, cv, 2.0f, Bb1, B0, B0, n);
        // acc += Tx4@W4 + Tx5@W5 (+BN stats)
        k_gemv2<<<gg, T, 0, stream>>>(Bb1, B0, Wt + 4 * WSZ, Wt + 5 * WSZ, nullptr, acc, st, n);
    };

    // branch 1: full graph
    branch(x, N, ei, E, Wt1, b1, degi1, fill1, dis1, rp1, cv1, B1_0, B1_1, acc1, st1);
    // branch 2
    k_scatter<<<cdiv(N * FIN, T), T, 0, stream>>>(x, cl1, N, xp1, cnt1);
    k_divcnt<<<cdiv(C1n * FIN, T), T, 0, stream>>>(xp1, cnt1, C1n);
    branch(xp1, C1n, eic1, E1, Wt2, b2, degi2, fill2, dis2, rp2, cv2, B2_0, B2_1, acc2, st2);
    // branch 3
    k_scatter<<<cdiv(N * FIN, T), T, 0, stream>>>(x, cl2, N, xp2, cnt2);
    k_divcnt<<<cdiv(C2n * FIN, T), T, 0, stream>>>(xp2, cnt2, C2n);
    branch(xp2, C2n, eic2, E2, Wt3, b3, degi3, fill3, dis3, rp3, cv3, B3_0, B3_1, acc3, st3);
    // BN coefficients for all three branches, then fused final mix
    k_bnprep3<<<1, 192, 0, stream>>>(st1, g1, bt1, 1.0f / (float)N,
                                     st2, g2, bt2, 1.0f / (float)C1n,
                                     st3, g3, bt3, 1.0f / (float)C2n,
                                     scsh1, scsh2, scsh3);
    k_final<<<cdiv(N, T), T, 0, stream>>>(acc1, scsh1, acc2, scsh2, cl1,
                                          acc3, scsh3, cl2,
                                          x, Wm, bm, (float*)d_out, N);
}

// Round 11
// 658.934 us; speedup vs baseline: 1.0331x; 1.0331x over previous
//
#include <hip/hip_runtime.h>
#include <algorithm>

#define FIN 24
#define NHID 64
#define NMIX 216
#define NOUT 6
#define BN_EPS 1e-5f

// ---------- CSR build ----------
__global__ void k_hist(const int* __restrict__ ei, int E, int* deg) {
    int e = blockIdx.x * blockDim.x + threadIdx.x;
    if (e < E) atomicAdd(&deg[ei[E + e]], 1);
}

// block-local exclusive scan over deg (n+1 elements, deg[i>=n]:=0); totals -> bsum
// also emits dis[i] = 1/sqrt(deg[i]) (0 if empty)
__global__ void k_scan_local(const int* __restrict__ deg, int n, int* rowptr, int* bsum,
                             float* __restrict__ dis) {
    __shared__ int s[256];
    int i = blockIdx.x * 256 + threadIdx.x;
    int v = (i < n) ? deg[i] : 0;
    if (i < n) dis[i] = v > 0 ? rsqrtf((float)v) : 0.f;
    s[threadIdx.x] = v;
    __syncthreads();
#pragma unroll
    for (int off = 1; off < 256; off <<= 1) {
        int x = (threadIdx.x >= off) ? s[threadIdx.x - off] : 0;
        __syncthreads();
        s[threadIdx.x] += x;
        __syncthreads();
    }
    if (i <= n) rowptr[i] = s[threadIdx.x] - v;  // exclusive
    if (threadIdx.x == 255) bsum[blockIdx.x] = s[255];
}

__global__ void k_scan_bsum(int* bsum, int nb) {
    __shared__ int s[256];
    int carry = 0;
    for (int base = 0; base < nb; base += 256) {
        int i = base + threadIdx.x;
        int v = (i < nb) ? bsum[i] : 0;
        s[threadIdx.x] = v;
        __syncthreads();
#pragma unroll
        for (int off = 1; off < 256; off <<= 1) {
            int x = (threadIdx.x >= off) ? s[threadIdx.x - off] : 0;
            __syncthreads();
            s[threadIdx.x] += x;
            __syncthreads();
        }
        if (i < nb) bsum[i] = s[threadIdx.x] - v + carry;
        carry += s[255];
        __syncthreads();
    }
}

__global__ void k_scan_add(int* rowptr, const int* __restrict__ bsum, int n) {
    int i = blockIdx.x * 256 + threadIdx.x;
    if (i <= n) rowptr[i] += bsum[blockIdx.x];
}

// fill CSR with packed (col, val) per edge
__global__ void k_fill(const int* __restrict__ ei, int E, const float* __restrict__ dis,
                       const int* __restrict__ rowptr, int* fill, int2* __restrict__ cv) {
    int e = blockIdx.x * blockDim.x + threadIdx.x;
    if (e >= E) return;
    int s = ei[e], d = ei[E + e];
    int slot = rowptr[d] + atomicAdd(&fill[d], 1);
    cv[slot] = make_int2(s, __float_as_int(-dis[s] * dis[d]));
}

// transpose 3 Cheb weight sets: W [6][24][64] -> Wt [6][64][24]
__global__ void k_wt3(const float* __restrict__ Wa, float* __restrict__ Ta,
                      const float* __restrict__ Wb, float* __restrict__ Tb,
                      const float* __restrict__ Wc, float* __restrict__ Tc) {
    int o = blockIdx.x * blockDim.x + threadIdx.x;  // 0 .. 3*9216-1
    int which = o / 9216, oo = o - which * 9216;
    const float* W = (which == 0) ? Wa : (which == 1) ? Wb : Wc;
    float* T       = (which == 0) ? Ta : (which == 1) ? Tb : Tc;
    int k = oo / 1536, r = oo - k * 1536;
    int j = r / FIN, f = r - j * FIN;
    T[oo] = W[k * 1536 + f * NHID + j];
}

// ---------- gather prop, thread per (dst node, float4 chunk) ----------
__global__ void k_propg(const int* __restrict__ rowptr, const int2* __restrict__ cv,
                        float scale, const float* __restrict__ h,
                        const float* __restrict__ prev, float* __restrict__ out, int n) {
    int idx = blockIdx.x * blockDim.x + threadIdx.x;
    if (idx >= n * 6) return;
    int d = idx / 6, q = idx - d * 6;
    int beg = rowptr[d], end = rowptr[d + 1];
    const float4* h4 = reinterpret_cast<const float4*>(h);
    float ax = 0.f, ay = 0.f, az = 0.f, aw = 0.f;
    float bx = 0.f, by = 0.f, bz = 0.f, bw = 0.f;
    int e = beg;
    for (; e + 2 <= end; e += 2) {
        int2 c0 = cv[e], c1 = cv[e + 1];
        float w0 = __int_as_float(c0.y), w1 = __int_as_float(c1.y);
        float4 h0 = h4[(size_t)c0.x * 6 + q];
        float4 h1 = h4[(size_t)c1.x * 6 + q];
        ax = fmaf(w0, h0.x, ax); ay = fmaf(w0, h0.y, ay);
        az = fmaf(w0, h0.z, az); aw = fmaf(w0, h0.w, aw);
        bx = fmaf(w1, h1.x, bx); by = fmaf(w1, h1.y, by);
        bz = fmaf(w1, h1.z, bz); bw = fmaf(w1, h1.w, bw);
    }
    if (e < end) {
        int2 c0 = cv[e];
        float w0 = __int_as_float(c0.y);
        float4 h0 = h4[(size_t)c0.x * 6 + q];
        ax = fmaf(w0, h0.x, ax); ay = fmaf(w0, h0.y, ay);
        az = fmaf(w0, h0.z, az); aw = fmaf(w0, h0.w, aw);
    }
    ax += bx; ay += by; az += bz; aw += bw;
    float4 r;
    if (prev) {
        float4 pv = reinterpret_cast<const float4*>(prev)[idx];
        r = make_float4(fmaf(scale, ax, -pv.x), fmaf(scale, ay, -pv.y),
                        fmaf(scale, az, -pv.z), fmaf(scale, aw, -pv.w));
    } else {
        r = make_float4(scale * ax, scale * ay, scale * az, scale * aw);
    }
    reinterpret_cast<float4*>(out)[idx] = r;
}

// ---------- single-pass 6-term gemv ----------
// acc[node][j] = bias[j] + sum_k S_k[node][:] @ Wt[k][j][:]   (k = 0..5)
// lane=j, wave-uniform node; 16 nodes per wave; per-lane accumulators accv[16]
// (statically indexed). S rows staged in wave-private LDS (no __syncthreads).
// No global loads in the k-loop except W_k columns (6 float4, once per k).
// BN stats (per-j sum/sumsq) fused.
__global__ void k_gemv6(const float* __restrict__ S0, const float* __restrict__ S1,
                        const float* __restrict__ S2, const float* __restrict__ S3,
                        const float* __restrict__ S4, const float* __restrict__ S5,
                        const float* __restrict__ Wt, const float* __restrict__ bias,
                        float* __restrict__ acc, float* __restrict__ stats, int n) {
    __shared__ float sb[4][6][16 * FIN];  // 4 waves x 6 mats x 384 floats = 36 KB
    int j = threadIdx.x & 63;
    int w = threadIdx.x >> 6;
    int nbase = blockIdx.x * 64 + w * 16;
    // ---- stage: 576 float4 per wave (96 per matrix = 16 nodes * 6); 9 per lane ----
#pragma unroll
    for (int k = 0; k < 9; ++k) {
        int i = k * 64 + j;                  // 0..575
        int half = i / 96;                   // 0..5 -> which S
        int j4 = i - half * 96;              // 0..95
        int nd = j4 / 6, q = j4 - nd * 6;    // nd: 0..15, q: 0..5
        int node = nbase + nd;
        const float* Sh = (half == 0) ? S0 : (half == 1) ? S1 : (half == 2) ? S2
                        : (half == 3) ? S3 : (half == 4) ? S4 : S5;
        const float* src = Sh + (size_t)node * FIN + q * 4;
        float4 v = (node < n) ? *reinterpret_cast<const float4*>(src)
                              : make_float4(0.f, 0.f, 0.f, 0.f);
        *reinterpret_cast<float4*>(&sb[w][half][j4 * 4]) = v;
    }
    // ---- accumulate: k outer, 16 statically-indexed accumulators ----
    float accv[16];
    {
        float bb = bias[j];
#pragma unroll
        for (int nd = 0; nd < 16; ++nd) accv[nd] = bb;
    }
#pragma unroll 1
    for (int k = 0; k < 6; ++k) {
        const float4* wp = reinterpret_cast<const float4*>(Wt + k * (NHID * FIN) + j * FIN);
        float4 w0 = wp[0], w1 = wp[1], w2 = wp[2], w3 = wp[3], w4 = wp[4], w5 = wp[5];
#pragma unroll
        for (int nd = 0; nd < 16; ++nd) {
            const float4* r = reinterpret_cast<const float4*>(&sb[w][k][nd * FIN]);
            float4 v0 = r[0], v1 = r[1], v2 = r[2], v3 = r[3], v4 = r[4], v5 = r[5];
            float a = accv[nd];
            a = fmaf(v0.x, w0.x, a); a = fmaf(v0.y, w0.y, a);
            a = fmaf(v0.z, w0.z, a); a = fmaf(v0.w, w0.w, a);
            a = fmaf(v1.x, w1.x, a); a = fmaf(v1.y, w1.y, a);
            a = fmaf(v1.z, w1.z, a); a = fmaf(v1.w, w1.w, a);
            a = fmaf(v2.x, w2.x, a); a = fmaf(v2.y, w2.y, a);
            a = fmaf(v2.z, w2.z, a); a = fmaf(v2.w, w2.w, a);
            a = fmaf(v3.x, w3.x, a); a = fmaf(v3.y, w3.y, a);
            a = fmaf(v3.z, w3.z, a); a = fmaf(v3.w, w3.w, a);
            a = fmaf(v4.x, w4.x, a); a = fmaf(v4.y, w4.y, a);
            a = fmaf(v4.z, w4.z, a); a = fmaf(v4.w, w4.w, a);
            a = fmaf(v5.x, w5.x, a); a = fmaf(v5.y, w5.y, a);
            a = fmaf(v5.z, w5.z, a); a = fmaf(v5.w, w5.w, a);
            accv[nd] = a;
        }
    }
    // ---- write + stats ----
    float sum = 0.f, sq = 0.f;
#pragma unroll
    for (int nd = 0; nd < 16; ++nd) {
        int node = nbase + nd;
        if (node < n) {
            acc[(size_t)node * NHID + j] = accv[nd];
            sum += accv[nd]; sq = fmaf(accv[nd], accv[nd], sq);
        }
    }
    __shared__ float rs[256], rq[256];
    rs[threadIdx.x] = sum; rq[threadIdx.x] = sq;
    __syncthreads();
    if (threadIdx.x < 64) {
        float s = rs[threadIdx.x] + rs[threadIdx.x + 64] + rs[threadIdx.x + 128] + rs[threadIdx.x + 192];
        float q = rq[threadIdx.x] + rq[threadIdx.x + 64] + rq[threadIdx.x + 128] + rq[threadIdx.x + 192];
        atomicAdd(&stats[threadIdx.x], s);
        atomicAdd(&stats[NHID + threadIdx.x], q);
    }
}

// BN coefficients for all 3 branches: scX[0:64]=scale, scX[64:128]=shift
__global__ void k_bnprep3(const float* __restrict__ st1, const float* __restrict__ g1,
                          const float* __restrict__ bt1, float inv1,
                          const float* __restrict__ st2, const float* __restrict__ g2,
                          const float* __restrict__ bt2, float inv2,
                          const float* __restrict__ st3, const float* __restrict__ g3,
                          const float* __restrict__ bt3, float inv3,
                          float* __restrict__ s1, float* __restrict__ s2,
                          float* __restrict__ s3) {
    int b = threadIdx.x >> 6, i = threadIdx.x & 63;
    const float* st = (b == 0) ? st1 : (b == 1) ? st2 : st3;
    const float* g  = (b == 0) ? g1  : (b == 1) ? g2  : g3;
    const float* bt = (b == 0) ? bt1 : (b == 1) ? bt2 : bt3;
    float inv       = (b == 0) ? inv1 : (b == 1) ? inv2 : inv3;
    float* so       = (b == 0) ? s1  : (b == 1) ? s2  : s3;
    float m = st[i] * inv;
    float v = st[NHID + i] * inv - m * m;
    float sc = g[i] * rsqrtf(v + BN_EPS);
    so[i] = sc;
    so[NHID + i] = fmaf(-m, sc, bt[i]);
}

// segment-mean scatter
__global__ void k_scatter(const float* __restrict__ x, const int* __restrict__ cl,
                          int n, float* xp, float* cnt) {
    int idx = blockIdx.x * blockDim.x + threadIdx.x;
    if (idx >= n * FIN) return;
    int node = idx / FIN, f = idx - node * FIN;
    int c = cl[node];
    atomicAdd(&xp[c * FIN + f], x[idx]);
    if (f == 0) atomicAdd(&cnt[c], 1.f);
}

__global__ void k_divcnt(float* xp, const float* __restrict__ cnt, int c) {
    int idx = blockIdx.x * blockDim.x + threadIdx.x;
    if (idx >= c * FIN) return;
    xp[idx] = xp[idx] / fmaxf(cnt[idx / FIN], 1.f);
}

// fused mix: thread per node; BN+ReLU for all three branches via precomputed
// scale/shift (uniform scalar loads); Wm/bm scalar-indexed.
__global__ void k_final(const float* __restrict__ acc1, const float* __restrict__ sc1,
                        const float* __restrict__ h2, const float* __restrict__ sc2,
                        const int* __restrict__ cl1,
                        const float* __restrict__ h3, const float* __restrict__ sc3,
                        const int* __restrict__ cl2,
                        const float* __restrict__ x, const float* __restrict__ Wm,
                        const float* __restrict__ bm, float* __restrict__ out, int n) {
    int t = blockIdx.x * blockDim.x + threadIdx.x;
    if (t >= n) return;
    float o[NOUT];
#pragma unroll
    for (int j = 0; j < NOUT; ++j) o[j] = bm[j];
    {
        const float4* r4 = reinterpret_cast<const float4*>(acc1 + (size_t)t * NHID);
#pragma unroll
        for (int i4 = 0; i4 < NHID / 4; ++i4) {
            float4 v = r4[i4];
            float hv[4] = {v.x, v.y, v.z, v.w};
#pragma unroll
            for (int c = 0; c < 4; ++c) {
                int i = i4 * 4 + c;
                float h = fmaxf(fmaf(hv[c], sc1[i], sc1[NHID + i]), 0.f);
#pragma unroll
                for (int j = 0; j < NOUT; ++j) o[j] = fmaf(h, Wm[i * NOUT + j], o[j]);
            }
        }
    }
    {
        const float4* r4 = reinterpret_cast<const float4*>(h2 + (size_t)cl1[t] * NHID);
#pragma unroll
        for (int i4 = 0; i4 < NHID / 4; ++i4) {
            float4 v = r4[i4];
            float hv[4] = {v.x, v.y, v.z, v.w};
#pragma unroll
            for (int c = 0; c < 4; ++c) {
                int hid = i4 * 4 + c;
                float h = fmaxf(fmaf(hv[c], sc2[hid], sc2[NHID + hid]), 0.f);
#pragma unroll
                for (int j = 0; j < NOUT; ++j) o[j] = fmaf(h, Wm[(NHID + hid) * NOUT + j], o[j]);
            }
        }
    }
    {
        const float4* r4 = reinterpret_cast<const float4*>(h3 + (size_t)cl2[t] * NHID);
#pragma unroll
        for (int i4 = 0; i4 < NHID / 4; ++i4) {
            float4 v = r4[i4];
            float hv[4] = {v.x, v.y, v.z, v.w};
#pragma unroll
            for (int c = 0; c < 4; ++c) {
                int hid = i4 * 4 + c;
                float h = fmaxf(fmaf(hv[c], sc3[hid], sc3[NHID + hid]), 0.f);
#pragma unroll
                for (int j = 0; j < NOUT; ++j) o[j] = fmaf(h, Wm[(2 * NHID + hid) * NOUT + j], o[j]);
            }
        }
    }
    {
        const float4* r4 = reinterpret_cast<const float4*>(x + (size_t)t * FIN);
#pragma unroll
        for (int i4 = 0; i4 < FIN / 4; ++i4) {
            float4 v = r4[i4];
            float hv[4] = {v.x, v.y, v.z, v.w};
#pragma unroll
            for (int c = 0; c < 4; ++c) {
                int i = 3 * NHID + i4 * 4 + c;
#pragma unroll
                for (int j = 0; j < NOUT; ++j) o[j] = fmaf(hv[c], Wm[i * NOUT + j], o[j]);
            }
        }
    }
    float* op = out + (size_t)t * NOUT;
#pragma unroll
    for (int j = 0; j < NOUT; ++j) op[j] = o[j];
}

extern "C" void kernel_launch(void* const* d_in, const int* in_sizes, int n_in,
                              void* d_out, int out_size, void* d_ws, size_t ws_size,
                              hipStream_t stream) {
    const int N = 200000, E = 800000;
    const int C1n = 20000, E1 = 80000;
    const int C2n = 2000, E2 = 8000;

    const float* x  = (const float*)d_in[0];
    const int* ei   = (const int*)d_in[1];
    const int* cl1  = (const int*)d_in[2];
    const int* cl2  = (const int*)d_in[3];
    const int* eic1 = (const int*)d_in[4];
    const int* eic2 = (const int*)d_in[5];
    const float* W1 = (const float*)d_in[6];  const float* b1 = (const float*)d_in[7];
    const float* g1 = (const float*)d_in[8];  const float* bt1 = (const float*)d_in[9];
    const float* W2 = (const float*)d_in[10]; const float* b2 = (const float*)d_in[11];
    const float* g2 = (const float*)d_in[12]; const float* bt2 = (const float*)d_in[13];
    const float* W3 = (const float*)d_in[14]; const float* b3 = (const float*)d_in[15];
    const float* g3 = (const float*)d_in[16]; const float* bt3 = (const float*)d_in[17];
    const float* Wm = (const float*)d_in[18]; const float* bm = (const float*)d_in[19];

    char* wb = (char*)d_ws;
    size_t off = 0;
    auto alloc = [&](size_t nwords) {
        void* p = wb + off; off += ((nwords + 3) & ~(size_t)3) * 4; return p;
    };
    // --- zero-region ---
    int* degi1 = (int*)alloc(N);   int* fill1 = (int*)alloc(N);
    int* degi2 = (int*)alloc(C1n); int* fill2 = (int*)alloc(C1n);
    int* degi3 = (int*)alloc(C2n); int* fill3 = (int*)alloc(C2n);
    float* st1 = (float*)alloc(128); float* st2 = (float*)alloc(128); float* st3 = (float*)alloc(128);
    float* xp1 = (float*)alloc((size_t)C1n * FIN); float* cnt1 = (float*)alloc(C1n);
    float* xp2 = (float*)alloc((size_t)C2n * FIN); float* cnt2 = (float*)alloc(C2n);
    size_t zero_bytes = off;
    // --- fully-overwritten region ---
    int* rp1 = (int*)alloc(N + 1);   int2* cv1 = (int2*)alloc(2 * (size_t)E);
    int* rp2 = (int*)alloc(C1n + 1); int2* cv2 = (int2*)alloc(2 * (size_t)E1);
    int* rp3 = (int*)alloc(C2n + 1); int2* cv3 = (int2*)alloc(2 * (size_t)E2);
    float* dis1 = (float*)alloc(N); float* dis2 = (float*)alloc(C1n); float* dis3 = (float*)alloc(C2n);
    int* bsum = (int*)alloc(1024);
    float* scsh1 = (float*)alloc(128); float* scsh2 = (float*)alloc(128); float* scsh3 = (float*)alloc(128);
    float* Wt1 = (float*)alloc(9216); float* Wt2 = (float*)alloc(9216); float* Wt3 = (float*)alloc(9216);
    float* T1[5]; for (int i = 0; i < 5; ++i) T1[i] = (float*)alloc((size_t)N * FIN);
    float* T2[5]; for (int i = 0; i < 5; ++i) T2[i] = (float*)alloc((size_t)C1n * FIN);
    float* T3[5]; for (int i = 0; i < 5; ++i) T3[i] = (float*)alloc((size_t)C2n * FIN);
    float* acc1 = (float*)alloc((size_t)N * NHID);
    float* acc2 = (float*)alloc((size_t)C1n * NHID);
    float* acc3 = (float*)alloc((size_t)C2n * NHID);
    if (off > ws_size) return;  // fail visibly if ws too small

    hipMemsetAsync(d_ws, 0, zero_bytes, stream);

    const int T = 256;
    auto cdiv = [](int a, int b) { return (a + b - 1) / b; };

    // transpose all Cheb weights up front (independent of everything else)
    k_wt3<<<cdiv(3 * 9216, T), T, 0, stream>>>(W1, Wt1, W2, Wt2, W3, Wt3);

    auto branch = [&](const float* xin, int n, const int* e, int Ecnt,
                      const float* Wt, const float* bb, int* degi, int* fill, float* dis,
                      int* rp, int2* cv, float** Tb, float* acc, float* st) {
        int ge = cdiv(Ecnt, T);
        int nb = cdiv(n + 1, 256);
        int gg = cdiv(n, 64);        // gemv6: one 64-node tile per block
        int gp = cdiv(n * 6, T);     // propg: thread per (node, chunk)
        // CSR build
        k_hist<<<ge, T, 0, stream>>>(e, Ecnt, degi);
        k_scan_local<<<nb, 256, 0, stream>>>(degi, n, rp, bsum, dis);
        k_scan_bsum<<<1, 256, 0, stream>>>(bsum, nb);
        k_scan_add<<<nb, 256, 0, stream>>>(rp, bsum, n);
        k_fill<<<ge, T, 0, stream>>>(e, Ecnt, dis, rp, fill, cv);
        // Chebyshev chain: Tb[0]=Tx1 .. Tb[4]=Tx5
        k_propg<<<gp, T, 0, stream>>>(rp, cv, 1.0f, xin, nullptr, Tb[0], n);
        k_propg<<<gp, T, 0, stream>>>(rp, cv, 2.0f, Tb[0], xin, Tb[1], n);
        k_propg<<<gp, T, 0, stream>>>(rp, cv, 2.0f, Tb[1], Tb[0], Tb[2], n);
        k_propg<<<gp, T, 0, stream>>>(rp, cv, 2.0f, Tb[2], Tb[1], Tb[3], n);
        k_propg<<<gp, T, 0, stream>>>(rp, cv, 2.0f, Tb[3], Tb[2], Tb[4], n);
        // single-pass 6-term gemv (+BN stats)
        k_gemv6<<<gg, T, 0, stream>>>(xin, Tb[0], Tb[1], Tb[2], Tb[3], Tb[4],
                                      Wt, bb, acc, st, n);
    };

    // branch 1: full graph
    branch(x, N, ei, E, Wt1, b1, degi1, fill1, dis1, rp1, cv1, T1, acc1, st1);
    // branch 2
    k_scatter<<<cdiv(N * FIN, T), T, 0, stream>>>(x, cl1, N, xp1, cnt1);
    k_divcnt<<<cdiv(C1n * FIN, T), T, 0, stream>>>(xp1, cnt1, C1n);
    branch(xp1, C1n, eic1, E1, Wt2, b2, degi2, fill2, dis2, rp2, cv2, T2, acc2, st2);
    // branch 3
    k_scatter<<<cdiv(N * FIN, T), T, 0, stream>>>(x, cl2, N, xp2, cnt2);
    k_divcnt<<<cdiv(C2n * FIN, T), T, 0, stream>>>(xp2, cnt2, C2n);
    branch(xp2, C2n, eic2, E2, Wt3, b3, degi3, fill3, dis3, rp3, cv3, T3, acc3, st3);
    // BN coefficients for all three branches, then fused final mix
    k_bnprep3<<<1, 192, 0, stream>>>(st1, g1, bt1, 1.0f / (float)N,
                                     st2, g2, bt2, 1.0f / (float)C1n,
                                     st3, g3, bt3, 1.0f / (float)C2n,
                                     scsh1, scsh2, scsh3);
    k_final<<<cdiv(N, T), T, 0, stream>>>(acc1, scsh1, acc2, scsh2, cl1,
                                          acc3, scsh3, cl2,
                                          x, Wm, bm, (float*)d_out, N);
}